// Round 15
// baseline (202.842 us; speedup 1.0000x reference)
//
#include <hip/hip_runtime.h>
#include <hip/hip_bf16.h>

#define BB 8
#define SS 512
#define HIDV 768
#define HH 12
#define DD 64
#define LV 81

typedef __attribute__((ext_vector_type(8))) short short8v;
typedef __attribute__((ext_vector_type(4))) short short4v;
typedef __attribute__((ext_vector_type(4))) float f32x4;

#define MFMA16(a, b, c) __builtin_amdgcn_mfma_f32_16x16x32_bf16(a, b, c, 0, 0, 0)

__device__ __forceinline__ short f2bf(float f) {
    __hip_bfloat16 h = __float2bfloat16(f);
    return *reinterpret_cast<short*>(&h);
}
__device__ __forceinline__ short f2h(float f) {
    _Float16 h = (_Float16)f; short s; __builtin_memcpy(&s, &h, 2); return s;
}
__device__ __forceinline__ float h2f(short s) {
    _Float16 h; __builtin_memcpy(&h, &s, 2); return (float)h;
}
__device__ __forceinline__ void gload16(const void* g, void* l) {
    __builtin_amdgcn_global_load_lds((const __attribute__((address_space(1))) void*)g,
                                     (__attribute__((address_space(3))) void*)l, 16, 0, 0);
}

// ---------------- LN tables -> lnkb bf16 [96][64], lnvT bf16 [64][96] ----------------
__global__ __launch_bounds__(256) void prep_ln_kernel(
    const float* __restrict__ rel_k, const float* __restrict__ rel_v,
    const float* __restrict__ gk, const float* __restrict__ bk,
    const float* __restrict__ gv, const float* __restrict__ bv,
    short* __restrict__ lnkb, short* __restrict__ lnvT) {
    __shared__ float ln_lds[2 * LV][DD];
    int t = threadIdx.x;
    if (t < 2 * LV) {
        bool isv = (t >= LV);
        int r = isv ? t - LV : t;
        const float* row = (isv ? rel_v : rel_k) + r * DD;
        const float* g = isv ? gv : gk;
        const float* be = isv ? bv : bk;
        float mu = 0.f;
        for (int d = 0; d < DD; ++d) mu += row[d];
        mu *= (1.f / DD);
        float var = 0.f;
        for (int d = 0; d < DD; ++d) { float x = row[d] - mu; var += x * x; }
        var *= (1.f / DD);
        float rs = rsqrtf(var + 1e-5f);
        for (int d = 0; d < DD; ++d) ln_lds[t][d] = (row[d] - mu) * rs * g[d] + be[d];
    }
    __syncthreads();
    for (int i = t; i < 96 * DD; i += 256) {
        int l = i >> 6, d = i & 63;
        lnkb[i] = (l < LV) ? f2bf(ln_lds[l][d]) : (short)0;
    }
    for (int i = t; i < DD * 96; i += 256) {
        int d = i / 96, ll = i - d * 96;
        lnvT[i] = (ll < LV) ? f2bf(ln_lds[LV + ll][d]) : (short)0;
    }
}

// ---------------- hidden f32 -> bf16 ----------------
__global__ __launch_bounds__(256) void conv_hidden_kernel(const float* __restrict__ in,
                                                          short* __restrict__ out) {
    int i = (blockIdx.x * 256 + threadIdx.x) * 4;
    float4 v = *reinterpret_cast<const float4*>(&in[i]);
    short4v o; o[0] = f2bf(v.x); o[1] = f2bf(v.y); o[2] = f2bf(v.z); o[3] = f2bf(v.w);
    *reinterpret_cast<short4v*>(&out[i]) = o;
}

// ---------------- W [k][n] f32 -> WT [n][k] bf16 (x3 via z) ----------------
__global__ __launch_bounds__(256) void transw_kernel(
    const float* __restrict__ Wq, const float* __restrict__ Wk, const float* __restrict__ Wv,
    short* __restrict__ WqT, short* __restrict__ WkT, short* __restrict__ WvT) {
    const float* W; short* O;
    if (blockIdx.z == 0) { W = Wq; O = WqT; }
    else if (blockIdx.z == 1) { W = Wk; O = WkT; }
    else { W = Wv; O = WvT; }
    __shared__ float tile[32][33];
    int k0 = blockIdx.y * 32, n0 = blockIdx.x * 32;
    int t = threadIdx.x;
    int r = t >> 3, c4 = (t & 7) * 4;
    float4 v = *reinterpret_cast<const float4*>(&W[(size_t)(k0 + r) * HIDV + n0 + c4]);
    tile[r][c4 + 0] = v.x; tile[r][c4 + 1] = v.y; tile[r][c4 + 2] = v.z; tile[r][c4 + 3] = v.w;
    __syncthreads();
    short4v o;
    o[0] = f2bf(tile[c4 + 0][r]); o[1] = f2bf(tile[c4 + 1][r]);
    o[2] = f2bf(tile[c4 + 2][r]); o[3] = f2bf(tile[c4 + 3][r]);
    *reinterpret_cast<short4v*>(&O[(size_t)(n0 + r) * HIDV + k0 + c4]) = o;
}

// ---------------- arc int32 [b][q][k] -> packed u32 arcP [b][k>>2][q] ----------------
__global__ __launch_bounds__(256) void arcpack_kernel(const int* __restrict__ arc,
                                                      unsigned int* __restrict__ arcP) {
    __shared__ unsigned int tbuf[64][129];
    const int tid = threadIdx.x;
    const int b = blockIdx.y;
    const int q0 = blockIdx.x * 64;
    for (int i = tid; i < 64 * 128; i += 256) {
        int r = i >> 7, c4 = i & 127;
        int4 v = *reinterpret_cast<const int4*>(&arc[((size_t)(b * SS) + q0 + r) * SS + 4 * c4]);
        tbuf[r][c4] = (unsigned)(v.x & 255) | ((unsigned)(v.y & 255) << 8) |
                      ((unsigned)(v.z & 255) << 16) | ((unsigned)(v.w & 255) << 24);
    }
    __syncthreads();
    for (int i = tid; i < 128 * 64; i += 256) {
        int k4 = i >> 6, r = i & 63;
        arcP[((size_t)b * 128 + k4) * SS + q0 + r] = tbuf[r][k4];
    }
}

// ---------------- QKV GEMM bf16 MFMA, 128x128 tile ----------------
// BM=128 BN=128 BK=64; 4 waves 2x2, each 64x64 acc[4][4]. BN spans 2 heads.
// V-transpose scratch: stride 136 (128 + 8 pad) -- r14's stride-72 bug fixed.
__global__ __launch_bounds__(256) void qkv_gemm_kernel(
    const short* __restrict__ Abf,
    const short* __restrict__ WqT, const short* __restrict__ WkT, const short* __restrict__ WvT,
    const float* __restrict__ bq, const float* __restrict__ bk, const float* __restrict__ bv,
    short* __restrict__ qo, short* __restrict__ ko, short* __restrict__ vto) {
    const short* Bt; const float* bias;
    int z = blockIdx.z;
    if (z == 0) { Bt = WqT; bias = bq; }
    else if (z == 1) { Bt = WkT; bias = bk; }
    else { Bt = WvT; bias = bv; }

    __shared__ short smem[17408];   // As 8192 + Bs 8192; epilogue reuses as Cs[128][136]
    short* As = smem;
    short* Bs = smem + 8192;

    const int tid = threadIdx.x;
    const int lane = tid & 63, w = tid >> 6;
    const int li = lane & 15, g = lane >> 4;
    const int wr = w >> 1, wc = w & 1;
    const int m0 = blockIdx.y * 128, n0 = blockIdx.x * 128;

    f32x4 acc[4][4];
#pragma unroll
    for (int ra = 0; ra < 4; ++ra)
#pragma unroll
        for (int cb = 0; cb < 4; ++cb)
            for (int r = 0; r < 4; ++r) acc[ra][cb][r] = 0.f;

#pragma unroll 1
    for (int k0 = 0; k0 < HIDV; k0 += 64) {
#pragma unroll
        for (int j = 0; j < 4; ++j) {
            int c = j * 256 + tid;            // 16B chunk id 0..1023
            int row = c >> 3, s = c & 7;
            int src = s ^ (row & 7);
            gload16(Abf + (size_t)(m0 + row) * HIDV + k0 + src * 8, As + c * 8);
            gload16(Bt + (size_t)(n0 + row) * HIDV + k0 + src * 8, Bs + c * 8);
        }
        __syncthreads();
#pragma unroll
        for (int c = 0; c < 2; ++c) {
            short8v af[4], bf[4];
#pragma unroll
            for (int ra = 0; ra < 4; ++ra) {
                int row = 64 * wr + 16 * ra + li;
                int chunk = (4 * c + g) ^ (row & 7);
                af[ra] = *reinterpret_cast<const short8v*>(&As[row * 64 + chunk * 8]);
            }
#pragma unroll
            for (int cb = 0; cb < 4; ++cb) {
                int rowb = 64 * wc + 16 * cb + li;
                int chunk = (4 * c + g) ^ (rowb & 7);
                bf[cb] = *reinterpret_cast<const short8v*>(&Bs[rowb * 64 + chunk * 8]);
            }
#pragma unroll
            for (int ra = 0; ra < 4; ++ra)
#pragma unroll
                for (int cb = 0; cb < 4; ++cb)
                    acc[ra][cb] = MFMA16(af[ra], bf[cb], acc[ra][cb]);
        }
        __syncthreads();
    }

    const int bidx = m0 >> 9;
    if (z < 2) {
        short* dst = (z == 0) ? qo : ko;
        float sc = (z == 0) ? 1.f : 0.125f;
#pragma unroll
        for (int ra = 0; ra < 4; ++ra)
#pragma unroll
            for (int cb = 0; cb < 4; ++cb) {
                int n = n0 + 64 * wc + 16 * cb + li;
                int h = n >> 6, d = n & 63;
                float bv_ = bias[n];
#pragma unroll
                for (int r = 0; r < 4; ++r) {
                    int m = m0 + 64 * wr + 16 * ra + 4 * g + r;
                    int s = m & 511;
                    dst[(((size_t)bidx * HH + h) * SS + s) * DD + d] =
                        f2bf((acc[ra][cb][r] + bv_) * sc);
                }
            }
    } else {
        // transpose via LDS: Cs[n-local][m-local], stride 136 (m-local is 128 wide)
        short* Cs = smem;   // 128*136 = 17408 shorts
#pragma unroll
        for (int ra = 0; ra < 4; ++ra)
#pragma unroll
            for (int cb = 0; cb < 4; ++cb) {
                int nl = 64 * wc + 16 * cb + li;
                float bv_ = bias[n0 + nl];
#pragma unroll
                for (int r = 0; r < 4; ++r) {
                    int ml = 64 * wr + 16 * ra + 4 * g + r;
                    Cs[nl * 136 + ml] = f2bf(acc[ra][cb][r] + bv_);
                }
            }
        __syncthreads();
        const int h0 = n0 >> 6;
#pragma unroll
        for (int j = 0; j < 8; ++j) {
            int c = tid + 256 * j;           // 0..2047 chunks of 8 shorts
            int col = c >> 4, s8 = (c & 15) * 8;
            short8v vv = *reinterpret_cast<const short8v*>(&Cs[col * 136 + s8]);
            int h = h0 + (col >> 6), dl = col & 63;
            *reinterpret_cast<short8v*>(
                &vto[(((size_t)bidx * HH + h) * DD + dl) * SS + (m0 & 511) + s8]) = vv;
        }
    }
}

// ---------------- fused attention (r13 structure, fp16 qrel) ----------------
__global__ __launch_bounds__(256, 2) void attn_kernel(
    const short* __restrict__ qb, const short* __restrict__ kb, const short* __restrict__ vt,
    const unsigned int* __restrict__ arcP, const float* __restrict__ maskp,
    const short* __restrict__ lnkb, const short* __restrict__ lnvT,
    float* __restrict__ outp) {
    __shared__ short qlds[4][16][84];     // fp16, 10.75 KB
    __shared__ float bucket[4][16][100];  // 25.6 KB

    const int tid = threadIdx.x;
    const int w = tid >> 6, lane = tid & 63;
    const int li = lane & 15, g = lane >> 4;
    const int bx = blockIdx.x;
    const int b = bx & 7;
    const int rest = bx >> 3;
    const int h = rest % HH, qt = rest / HH;
    const int bh = b * HH + h;
    const int q0 = qt * 64 + w * 16;

    const short* kbp = kb + (size_t)bh * SS * DD;
    const short* vbp = vt + (size_t)bh * DD * SS;
    const unsigned int* apb = arcP + (size_t)b * 128 * SS;
    const float* mkb = maskp + (size_t)b * SS;

    for (int i = lane; i < 16 * 100; i += 64) (&bucket[w][0][0])[i] = 0.f;

    short8v qf0, qf1;
    {
        const short* qrow = qb + ((size_t)bh * SS + q0 + li) * DD + 8 * g;
        qf0 = *reinterpret_cast<const short8v*>(qrow);
        qf1 = *reinterpret_cast<const short8v*>(qrow + 32);
    }

    // qrel tile via MFMA -> fp16 LDS (wave-private)
#pragma unroll
    for (int ct = 0; ct < 6; ++ct) {
        f32x4 a = {0.f, 0.f, 0.f, 0.f};
        short8v b0 = *reinterpret_cast<const short8v*>(&lnkb[(16 * ct + li) * DD + 8 * g]);
        short8v b1 = *reinterpret_cast<const short8v*>(&lnkb[(16 * ct + li) * DD + 32 + 8 * g]);
        a = MFMA16(qf0, b0, a);
        a = MFMA16(qf1, b1, a);
        if (16 * ct + li < 84)
#pragma unroll
            for (int r = 0; r < 4; ++r) qlds[w][4 * g + r][16 * ct + li] = f2h(a[r]);
    }

    f32x4 oacc[4];
    for (int t = 0; t < 4; ++t) for (int r = 0; r < 4; ++r) oacc[t][r] = 0.f;

    short8v kf[8];
    unsigned int a_[2][4];
    float4 m_[2][4];
#pragma unroll
    for (int t = 0; t < 4; ++t) {
        const short* kr = kbp + (size_t)(16 * t + li) * DD + 8 * g;
        kf[2 * t] = *reinterpret_cast<const short8v*>(kr);
        kf[2 * t + 1] = *reinterpret_cast<const short8v*>(kr + 32);
        a_[0][t] = apb[(size_t)(4 * t + g) * SS + q0 + li];
        m_[0][t] = *reinterpret_cast<const float4*>(&mkb[16 * t + 4 * g]);
    }

#pragma unroll
    for (int kt = 0; kt < 8; ++kt) {
        const int cur = kt & 1, nxt = cur ^ 1;
        const int kb0 = kt * 64;

        f32x4 sacc[4];
#pragma unroll
        for (int t = 0; t < 4; ++t) {
            f32x4 a = {0.f, 0.f, 0.f, 0.f};
            a = MFMA16(kf[2 * t], qf0, a);
            a = MFMA16(kf[2 * t + 1], qf1, a);
            sacc[t] = a;
        }

        if (kt < 7) {
#pragma unroll
            for (int t = 0; t < 4; ++t) {
                const short* kr = kbp + (size_t)(kb0 + 64 + 16 * t + li) * DD + 8 * g;
                kf[2 * t] = *reinterpret_cast<const short8v*>(kr);
                kf[2 * t + 1] = *reinterpret_cast<const short8v*>(kr + 32);
                a_[nxt][t] = apb[(size_t)((kt + 1) * 16 + 4 * t + g) * SS + q0 + li];
                m_[nxt][t] = *reinterpret_cast<const float4*>(&mkb[kb0 + 64 + 16 * t + 4 * g]);
            }
        }

        float p[16];
#pragma unroll
        for (int t = 0; t < 4; ++t) {
            const unsigned int a4 = a_[cur][t];
            float qv0 = h2f(qlds[w][li][a4 & 255]);
            float qv1 = h2f(qlds[w][li][(a4 >> 8) & 255]);
            float qv2 = h2f(qlds[w][li][(a4 >> 16) & 255]);
            float qv3 = h2f(qlds[w][li][a4 >> 24]);
            p[4 * t + 0] = __expf(sacc[t][0] + qv0 + m_[cur][t].x);
            p[4 * t + 1] = __expf(sacc[t][1] + qv1 + m_[cur][t].y);
            p[4 * t + 2] = __expf(sacc[t][2] + qv2 + m_[cur][t].z);
            p[4 * t + 3] = __expf(sacc[t][3] + qv3 + m_[cur][t].w);
        }

#pragma unroll
        for (int t = 0; t < 4; ++t) {
            const unsigned int a4 = a_[cur][t];
            unsafeAtomicAdd(&bucket[w][li][a4 & 255], p[4 * t + 0]);
            unsafeAtomicAdd(&bucket[w][li][(a4 >> 8) & 255], p[4 * t + 1]);
            unsafeAtomicAdd(&bucket[w][li][(a4 >> 16) & 255], p[4 * t + 2]);
            unsafeAtomicAdd(&bucket[w][li][a4 >> 24], p[4 * t + 3]);
        }

        short8v pfrag[2];
#pragma unroll
        for (int t = 0; t < 4; ++t)
#pragma unroll
            for (int r = 0; r < 4; ++r) pfrag[t >> 1][4 * (t & 1) + r] = f2bf(p[4 * t + r]);
#pragma unroll
        for (int dt = 0; dt < 2; ++dt) {
#pragma unroll
            for (int t2 = 0; t2 < 4; ++t2) {
                const short* vr = vbp + (size_t)(16 * t2 + li) * SS + kb0 + 32 * dt + 4 * g;
                short4v v0 = *reinterpret_cast<const short4v*>(vr);
                short4v v1 = *reinterpret_cast<const short4v*>(vr + 16);
                short8v vf;
                vf[0] = v0[0]; vf[1] = v0[1]; vf[2] = v0[2]; vf[3] = v0[3];
                vf[4] = v1[0]; vf[5] = v1[1]; vf[6] = v1[2]; vf[7] = v1[3];
                oacc[t2] = MFMA16(pfrag[dt], vf, oacc[t2]);
            }
        }
    }

    float lsum = 0.f;
#pragma unroll
    for (int j = 0; j < 24; ++j) {
        int c = 24 * g + j;
        lsum += (c < 81) ? bucket[w][li][c] : 0.f;
    }
    lsum += __shfl_xor(lsum, 16);
    lsum += __shfl_xor(lsum, 32);
    float inv = 1.f / lsum;
    float invr[4];
#pragma unroll
    for (int r = 0; r < 4; ++r) invr[r] = __shfl(inv, 4 * g + r);

    f32x4 racc[4];
    for (int t = 0; t < 4; ++t) for (int r = 0; r < 4; ++r) racc[t][r] = 0.f;
#pragma unroll
    for (int c = 0; c < 3; ++c) {
        f32x4 b0 = *reinterpret_cast<const f32x4*>(&bucket[w][li][8 * g + 32 * c]);
        f32x4 b1 = *reinterpret_cast<const f32x4*>(&bucket[w][li][8 * g + 32 * c + 4]);
        short8v bfr;
        bfr[0] = f2bf(b0[0]); bfr[1] = f2bf(b0[1]); bfr[2] = f2bf(b0[2]); bfr[3] = f2bf(b0[3]);
        bfr[4] = f2bf(b1[0]); bfr[5] = f2bf(b1[1]); bfr[6] = f2bf(b1[2]); bfr[7] = f2bf(b1[3]);
#pragma unroll
        for (int t2 = 0; t2 < 4; ++t2) {
            short8v lf = *reinterpret_cast<const short8v*>(
                &lnvT[(16 * t2 + li) * 96 + 8 * g + 32 * c]);
            racc[t2] = MFMA16(bfr, lf, racc[t2]);
        }
    }

#pragma unroll
    for (int t2 = 0; t2 < 4; ++t2)
#pragma unroll
        for (int r = 0; r < 4; ++r) {
            int row = q0 + 4 * g + r;
            outp[((size_t)b * SS + row) * HIDV + h * DD + 16 * t2 + li] =
                (oacc[t2][r] + racc[t2][r]) * invr[r];
        }
}

// ---------------- launcher ----------------
extern "C" void kernel_launch(void* const* d_in, const int* in_sizes, int n_in,
                              void* d_out, int out_size, void* d_ws, size_t ws_size,
                              hipStream_t stream) {
    const float* hidden = (const float*)d_in[0];
    const float* mask   = (const float*)d_in[1];
    const int*   arc    = (const int*)d_in[2];
    const float* Wq = (const float*)d_in[3];
    const float* bq = (const float*)d_in[4];
    const float* Wk = (const float*)d_in[5];
    const float* bk = (const float*)d_in[6];
    const float* Wv = (const float*)d_in[7];
    const float* bv = (const float*)d_in[8];
    const float* rel_k = (const float*)d_in[9];
    const float* rel_v = (const float*)d_in[10];
    const float* lng_k = (const float*)d_in[11];
    const float* lnb_k = (const float*)d_in[12];
    const float* lng_v = (const float*)d_in[13];
    const float* lnb_v = (const float*)d_in[14];
    float* out = (float*)d_out;

    char* p = (char*)d_ws;
    auto carve = [&](size_t bytes) { char* r = p; p += (bytes + 255) & ~(size_t)255; return r; };
    short* lnkb = (short*)carve((size_t)96 * DD * 2);
    short* lnvT = (short*)carve((size_t)DD * 96 * 2);
    short* hbf  = (short*)carve((size_t)BB * SS * HIDV * 2);
    short* WqT  = (short*)carve((size_t)HIDV * HIDV * 2);
    short* WkT  = (short*)carve((size_t)HIDV * HIDV * 2);
    short* WvT  = (short*)carve((size_t)HIDV * HIDV * 2);
    const size_t per = (size_t)BB * HH * SS * DD;
    short* qbuf = (short*)carve(per * 2);
    short* kbuf = (short*)carve(per * 2);
    short* vtb  = (short*)carve(per * 2);
    unsigned int* arcP = (unsigned int*)carve((size_t)BB * 128 * SS * 4);

    prep_ln_kernel<<<1, 256, 0, stream>>>(rel_k, rel_v, lng_k, lnb_k, lng_v, lnb_v, lnkb, lnvT);
    conv_hidden_kernel<<<(BB * SS * HIDV) / 1024, 256, 0, stream>>>(hidden, hbf);
    transw_kernel<<<dim3(24, 24, 3), 256, 0, stream>>>(Wq, Wk, Wv, WqT, WkT, WvT);
    arcpack_kernel<<<dim3(8, BB), 256, 0, stream>>>(arc, arcP);
    qkv_gemm_kernel<<<dim3(HIDV / 128, (BB * SS) / 128, 3), 256, 0, stream>>>(
        hbf, WqT, WkT, WvT, bq, bk, bv, qbuf, kbuf, vtb);
    attn_kernel<<<dim3(BB * HH * 8), 256, 0, stream>>>(
        qbuf, kbuf, vtb, arcP, mask, lnkb, lnvT, out);
}

// Round 16
// 196.016 us; speedup vs baseline: 1.0348x; 1.0348x over previous
//
#include <hip/hip_runtime.h>
#include <hip/hip_bf16.h>

#define BB 8
#define SS 512
#define HIDV 768
#define HH 12
#define DD 64
#define LV 81

typedef __attribute__((ext_vector_type(8))) short short8v;
typedef __attribute__((ext_vector_type(4))) short short4v;
typedef __attribute__((ext_vector_type(4))) float f32x4;

#define MFMA16(a, b, c) __builtin_amdgcn_mfma_f32_16x16x32_bf16(a, b, c, 0, 0, 0)

__device__ __forceinline__ short f2bf(float f) {
    __hip_bfloat16 h = __float2bfloat16(f);
    return *reinterpret_cast<short*>(&h);
}
__device__ __forceinline__ void gload16(const void* g, void* l) {
    __builtin_amdgcn_global_load_lds((const __attribute__((address_space(1))) void*)g,
                                     (__attribute__((address_space(3))) void*)l, 16, 0, 0);
}

// ---------------- LN tables -> lnkb bf16 [96][64], lnvT bf16 [64][96] ----------------
__global__ __launch_bounds__(256) void prep_ln_kernel(
    const float* __restrict__ rel_k, const float* __restrict__ rel_v,
    const float* __restrict__ gk, const float* __restrict__ bk,
    const float* __restrict__ gv, const float* __restrict__ bv,
    short* __restrict__ lnkb, short* __restrict__ lnvT) {
    __shared__ float ln_lds[2 * LV][DD];
    int t = threadIdx.x;
    if (t < 2 * LV) {
        bool isv = (t >= LV);
        int r = isv ? t - LV : t;
        const float* row = (isv ? rel_v : rel_k) + r * DD;
        const float* g = isv ? gv : gk;
        const float* be = isv ? bv : bk;
        float mu = 0.f;
        for (int d = 0; d < DD; ++d) mu += row[d];
        mu *= (1.f / DD);
        float var = 0.f;
        for (int d = 0; d < DD; ++d) { float x = row[d] - mu; var += x * x; }
        var *= (1.f / DD);
        float rs = rsqrtf(var + 1e-5f);
        for (int d = 0; d < DD; ++d) ln_lds[t][d] = (row[d] - mu) * rs * g[d] + be[d];
    }
    __syncthreads();
    for (int i = t; i < 96 * DD; i += 256) {
        int l = i >> 6, d = i & 63;
        lnkb[i] = (l < LV) ? f2bf(ln_lds[l][d]) : (short)0;
    }
    for (int i = t; i < DD * 96; i += 256) {
        int d = i / 96, ll = i - d * 96;
        lnvT[i] = (ll < LV) ? f2bf(ln_lds[LV + ll][d]) : (short)0;
    }
}

// ---------------- hidden f32 -> bf16 ----------------
__global__ __launch_bounds__(256) void conv_hidden_kernel(const float* __restrict__ in,
                                                          short* __restrict__ out) {
    int i = (blockIdx.x * 256 + threadIdx.x) * 4;
    float4 v = *reinterpret_cast<const float4*>(&in[i]);
    short4v o; o[0] = f2bf(v.x); o[1] = f2bf(v.y); o[2] = f2bf(v.z); o[3] = f2bf(v.w);
    *reinterpret_cast<short4v*>(&out[i]) = o;
}

// ---------------- W [k][n] f32 -> WT [n][k] bf16 (x3 via z) ----------------
__global__ __launch_bounds__(256) void transw_kernel(
    const float* __restrict__ Wq, const float* __restrict__ Wk, const float* __restrict__ Wv,
    short* __restrict__ WqT, short* __restrict__ WkT, short* __restrict__ WvT) {
    const float* W; short* O;
    if (blockIdx.z == 0) { W = Wq; O = WqT; }
    else if (blockIdx.z == 1) { W = Wk; O = WkT; }
    else { W = Wv; O = WvT; }
    __shared__ float tile[32][33];
    int k0 = blockIdx.y * 32, n0 = blockIdx.x * 32;
    int t = threadIdx.x;
    int r = t >> 3, c4 = (t & 7) * 4;
    float4 v = *reinterpret_cast<const float4*>(&W[(size_t)(k0 + r) * HIDV + n0 + c4]);
    tile[r][c4 + 0] = v.x; tile[r][c4 + 1] = v.y; tile[r][c4 + 2] = v.z; tile[r][c4 + 3] = v.w;
    __syncthreads();
    short4v o;
    o[0] = f2bf(tile[c4 + 0][r]); o[1] = f2bf(tile[c4 + 1][r]);
    o[2] = f2bf(tile[c4 + 2][r]); o[3] = f2bf(tile[c4 + 3][r]);
    *reinterpret_cast<short4v*>(&O[(size_t)(n0 + r) * HIDV + k0 + c4]) = o;
}

// ---------------- arc int32 [b][q][k] -> packed u32 arcP [b][k>>2][q] ----------------
__global__ __launch_bounds__(256) void arcpack_kernel(const int* __restrict__ arc,
                                                      unsigned int* __restrict__ arcP) {
    __shared__ unsigned int tbuf[64][129];
    const int tid = threadIdx.x;
    const int b = blockIdx.y;
    const int q0 = blockIdx.x * 64;
    for (int i = tid; i < 64 * 128; i += 256) {
        int r = i >> 7, c4 = i & 127;
        int4 v = *reinterpret_cast<const int4*>(&arc[((size_t)(b * SS) + q0 + r) * SS + 4 * c4]);
        tbuf[r][c4] = (unsigned)(v.x & 255) | ((unsigned)(v.y & 255) << 8) |
                      ((unsigned)(v.z & 255) << 16) | ((unsigned)(v.w & 255) << 24);
    }
    __syncthreads();
    for (int i = tid; i < 128 * 64; i += 256) {
        int k4 = i >> 6, r = i & 63;
        arcP[((size_t)b * 128 + k4) * SS + q0 + r] = tbuf[r][k4];
    }
}

// ---------------- QKV GEMM bf16 MFMA (64x64, proven r13 version) ----------------
__global__ __launch_bounds__(256) void qkv_gemm_kernel(
    const short* __restrict__ Abf,
    const short* __restrict__ WqT, const short* __restrict__ WkT, const short* __restrict__ WvT,
    const float* __restrict__ bq, const float* __restrict__ bk, const float* __restrict__ bv,
    short* __restrict__ qo, short* __restrict__ ko, short* __restrict__ vto) {
    const short* Bt; const float* bias;
    int z = blockIdx.z;
    if (z == 0) { Bt = WqT; bias = bq; }
    else if (z == 1) { Bt = WkT; bias = bk; }
    else { Bt = WvT; bias = bv; }

    __shared__ short smem[8192];
    short* As = smem;
    short* Bs = smem + 4096;

    const int tid = threadIdx.x;
    const int lane = tid & 63, w = tid >> 6;
    const int li = lane & 15, g = lane >> 4;
    const int wr = w >> 1, wc = w & 1;
    const int m0 = blockIdx.y * 64, n0 = blockIdx.x * 64;

    f32x4 acc[2][2];
    for (int ra = 0; ra < 2; ++ra)
        for (int cb = 0; cb < 2; ++cb)
            for (int r = 0; r < 4; ++r) acc[ra][cb][r] = 0.f;

#pragma unroll 1
    for (int k0 = 0; k0 < HIDV; k0 += 64) {
#pragma unroll
        for (int j = 0; j < 2; ++j) {
            int c = j * 256 + tid;
            int row = c >> 3, s = c & 7;
            int src = s ^ (row & 7);
            gload16(Abf + (size_t)(m0 + row) * HIDV + k0 + src * 8, As + c * 8);
            gload16(Bt + (size_t)(n0 + row) * HIDV + k0 + src * 8, Bs + c * 8);
        }
        __syncthreads();
#pragma unroll
        for (int c = 0; c < 2; ++c) {
            short8v af[2], bf[2];
#pragma unroll
            for (int ra = 0; ra < 2; ++ra) {
                int row = 32 * wr + 16 * ra + li;
                int chunk = (4 * c + g) ^ (row & 7);
                af[ra] = *reinterpret_cast<const short8v*>(&As[row * 64 + chunk * 8]);
            }
#pragma unroll
            for (int cb = 0; cb < 2; ++cb) {
                int rowb = 32 * wc + 16 * cb + li;
                int chunk = (4 * c + g) ^ (rowb & 7);
                bf[cb] = *reinterpret_cast<const short8v*>(&Bs[rowb * 64 + chunk * 8]);
            }
#pragma unroll
            for (int ra = 0; ra < 2; ++ra)
#pragma unroll
                for (int cb = 0; cb < 2; ++cb)
                    acc[ra][cb] = MFMA16(af[ra], bf[cb], acc[ra][cb]);
        }
        __syncthreads();
    }

    const int h = n0 >> 6;
    const int bidx = m0 >> 9;
    if (z < 2) {
        short* dst = (z == 0) ? qo : ko;
        float sc = (z == 0) ? 1.f : 0.125f;
#pragma unroll
        for (int ra = 0; ra < 2; ++ra)
#pragma unroll
            for (int cb = 0; cb < 2; ++cb) {
                int n = 32 * wc + 16 * cb + li;
                float bv_ = bias[n0 + n];
#pragma unroll
                for (int r = 0; r < 4; ++r) {
                    int m = m0 + 32 * wr + 16 * ra + 4 * g + r;
                    int s = m & 511;
                    dst[(((size_t)bidx * HH + h) * SS + s) * DD + n] =
                        f2bf((acc[ra][cb][r] + bv_) * sc);
                }
            }
    } else {
        short* Cs = smem;
#pragma unroll
        for (int ra = 0; ra < 2; ++ra)
#pragma unroll
            for (int cb = 0; cb < 2; ++cb) {
                int nl = 32 * wc + 16 * cb + li;
                float bv_ = bias[n0 + nl];
#pragma unroll
                for (int r = 0; r < 4; ++r) {
                    int ml = 32 * wr + 16 * ra + 4 * g + r;
                    Cs[nl * 72 + ml] = f2bf(acc[ra][cb][r] + bv_);
                }
            }
        __syncthreads();
        for (int c = tid; c < 512; c += 256) {
            int dl = c >> 3, s8 = (c & 7) * 8;
            short8v vv = *reinterpret_cast<const short8v*>(&Cs[dl * 72 + s8]);
            *reinterpret_cast<short8v*>(
                &vto[(((size_t)bidx * HH + h) * DD + dl) * SS + (m0 & 511) + s8]) = vv;
        }
    }
}

// ---------------- fused attention (r13 + gather hoisted one tile ahead) ----------------
__global__ __launch_bounds__(256, 2) void attn_kernel(
    const short* __restrict__ qb, const short* __restrict__ kb, const short* __restrict__ vt,
    const unsigned int* __restrict__ arcP, const float* __restrict__ maskp,
    const short* __restrict__ lnkb, const short* __restrict__ lnvT,
    float* __restrict__ outp) {
    __shared__ float qlds[4][16][84];     // 21.5 KB (f32, r13 config)
    __shared__ float bucket[4][16][100];  // 25.6 KB

    const int tid = threadIdx.x;
    const int w = tid >> 6, lane = tid & 63;
    const int li = lane & 15, g = lane >> 4;
    const int bx = blockIdx.x;
    const int b = bx & 7;
    const int rest = bx >> 3;
    const int h = rest % HH, qt = rest / HH;
    const int bh = b * HH + h;
    const int q0 = qt * 64 + w * 16;

    const short* kbp = kb + (size_t)bh * SS * DD;
    const short* vbp = vt + (size_t)bh * DD * SS;
    const unsigned int* apb = arcP + (size_t)b * 128 * SS;
    const float* mkb = maskp + (size_t)b * SS;

    for (int i = lane; i < 16 * 100; i += 64) (&bucket[w][0][0])[i] = 0.f;

    short8v qf0, qf1;
    {
        const short* qrow = qb + ((size_t)bh * SS + q0 + li) * DD + 8 * g;
        qf0 = *reinterpret_cast<const short8v*>(qrow);
        qf1 = *reinterpret_cast<const short8v*>(qrow + 32);
    }

    // qrel tile via MFMA (wave-private, f32 LDS)
#pragma unroll
    for (int ct = 0; ct < 6; ++ct) {
        f32x4 a = {0.f, 0.f, 0.f, 0.f};
        short8v b0 = *reinterpret_cast<const short8v*>(&lnkb[(16 * ct + li) * DD + 8 * g]);
        short8v b1 = *reinterpret_cast<const short8v*>(&lnkb[(16 * ct + li) * DD + 32 + 8 * g]);
        a = MFMA16(qf0, b0, a);
        a = MFMA16(qf1, b1, a);
        if (16 * ct + li < 84)
#pragma unroll
            for (int r = 0; r < 4; ++r) qlds[w][4 * g + r][16 * ct + li] = a[r];
    }

    f32x4 oacc[4];
    for (int t = 0; t < 4; ++t) for (int r = 0; r < 4; ++r) oacc[t][r] = 0.f;

    // pipeline state: K frags, arc/mask dbuf, and gathered qrel values (1 tile ahead)
    short8v kf[8];
    unsigned int a_[2][4];
    float4 m_[2][4];
    float qv_[2][16];
#pragma unroll
    for (int t = 0; t < 4; ++t) {
        const short* kr = kbp + (size_t)(16 * t + li) * DD + 8 * g;
        kf[2 * t] = *reinterpret_cast<const short8v*>(kr);
        kf[2 * t + 1] = *reinterpret_cast<const short8v*>(kr + 32);
        a_[0][t] = apb[(size_t)(4 * t + g) * SS + q0 + li];
        m_[0][t] = *reinterpret_cast<const float4*>(&mkb[16 * t + 4 * g]);
    }
    // gather tile-0 qrel values (after qlds writes; same wave => no barrier needed)
#pragma unroll
    for (int t = 0; t < 4; ++t) {
        const unsigned int a4 = a_[0][t];
        qv_[0][4 * t + 0] = qlds[w][li][a4 & 255];
        qv_[0][4 * t + 1] = qlds[w][li][(a4 >> 8) & 255];
        qv_[0][4 * t + 2] = qlds[w][li][(a4 >> 16) & 255];
        qv_[0][4 * t + 3] = qlds[w][li][a4 >> 24];
    }

#pragma unroll
    for (int kt = 0; kt < 8; ++kt) {
        const int cur = kt & 1, nxt = cur ^ 1;
        const int kb0 = kt * 64;

        // 1. QK^T consumes kf (K pre-scaled 0.125); C[k=16t+4g+r][q=li]
        f32x4 sacc[4];
#pragma unroll
        for (int t = 0; t < 4; ++t) {
            f32x4 a = {0.f, 0.f, 0.f, 0.f};
            a = MFMA16(kf[2 * t], qf0, a);
            a = MFMA16(kf[2 * t + 1], qf1, a);
            sacc[t] = a;
        }

        // 2. prefetch next tile's K/arc/mask, then gather next tile's qrel values
        if (kt < 7) {
#pragma unroll
            for (int t = 0; t < 4; ++t) {
                const short* kr = kbp + (size_t)(kb0 + 64 + 16 * t + li) * DD + 8 * g;
                kf[2 * t] = *reinterpret_cast<const short8v*>(kr);
                kf[2 * t + 1] = *reinterpret_cast<const short8v*>(kr + 32);
                a_[nxt][t] = apb[(size_t)((kt + 1) * 16 + 4 * t + g) * SS + q0 + li];
                m_[nxt][t] = *reinterpret_cast<const float4*>(&mkb[kb0 + 64 + 16 * t + 4 * g]);
            }
#pragma unroll
            for (int t = 0; t < 4; ++t) {
                const unsigned int a4 = a_[nxt][t];
                qv_[nxt][4 * t + 0] = qlds[w][li][a4 & 255];
                qv_[nxt][4 * t + 1] = qlds[w][li][(a4 >> 8) & 255];
                qv_[nxt][4 * t + 2] = qlds[w][li][(a4 >> 16) & 255];
                qv_[nxt][4 * t + 3] = qlds[w][li][a4 >> 24];
            }
        }

        // 3. exp from registers only (no LDS reads on the critical path)
        float p[16];
#pragma unroll
        for (int t = 0; t < 4; ++t) {
            p[4 * t + 0] = __expf(sacc[t][0] + qv_[cur][4 * t + 0] + m_[cur][t].x);
            p[4 * t + 1] = __expf(sacc[t][1] + qv_[cur][4 * t + 1] + m_[cur][t].y);
            p[4 * t + 2] = __expf(sacc[t][2] + qv_[cur][4 * t + 2] + m_[cur][t].z);
            p[4 * t + 3] = __expf(sacc[t][3] + qv_[cur][4 * t + 3] + m_[cur][t].w);
        }

        // 4. HW LDS atomics
#pragma unroll
        for (int t = 0; t < 4; ++t) {
            const unsigned int a4 = a_[cur][t];
            unsafeAtomicAdd(&bucket[w][li][a4 & 255], p[4 * t + 0]);
            unsafeAtomicAdd(&bucket[w][li][(a4 >> 8) & 255], p[4 * t + 1]);
            unsafeAtomicAdd(&bucket[w][li][(a4 >> 16) & 255], p[4 * t + 2]);
            unsafeAtomicAdd(&bucket[w][li][a4 >> 24], p[4 * t + 3]);
        }

        // 5. pack P and PV
        short8v pfrag[2];
#pragma unroll
        for (int t = 0; t < 4; ++t)
#pragma unroll
            for (int r = 0; r < 4; ++r) pfrag[t >> 1][4 * (t & 1) + r] = f2bf(p[4 * t + r]);
#pragma unroll
        for (int dt = 0; dt < 2; ++dt) {
#pragma unroll
            for (int t2 = 0; t2 < 4; ++t2) {
                const short* vr = vbp + (size_t)(16 * t2 + li) * SS + kb0 + 32 * dt + 4 * g;
                short4v v0 = *reinterpret_cast<const short4v*>(vr);
                short4v v1 = *reinterpret_cast<const short4v*>(vr + 16);
                short8v vf;
                vf[0] = v0[0]; vf[1] = v0[1]; vf[2] = v0[2]; vf[3] = v0[3];
                vf[4] = v1[0]; vf[5] = v1[1]; vf[6] = v1[2]; vf[7] = v1[3];
                oacc[t2] = MFMA16(pfrag[dt], vf, oacc[t2]);
            }
        }
    }

    // rowsum for q=li from buckets
    float lsum = 0.f;
#pragma unroll
    for (int j = 0; j < 24; ++j) {
        int c = 24 * g + j;
        lsum += (c < 81) ? bucket[w][li][c] : 0.f;
    }
    lsum += __shfl_xor(lsum, 16);
    lsum += __shfl_xor(lsum, 32);
    float inv = 1.f / lsum;
    float invr[4];
#pragma unroll
    for (int r = 0; r < 4; ++r) invr[r] = __shfl(inv, 4 * g + r);

    // rel-V: racc = bucket @ lnvT (labels zero-padded to 96)
    f32x4 racc[4];
    for (int t = 0; t < 4; ++t) for (int r = 0; r < 4; ++r) racc[t][r] = 0.f;
#pragma unroll
    for (int c = 0; c < 3; ++c) {
        f32x4 b0 = *reinterpret_cast<const f32x4*>(&bucket[w][li][8 * g + 32 * c]);
        f32x4 b1 = *reinterpret_cast<const f32x4*>(&bucket[w][li][8 * g + 32 * c + 4]);
        short8v bfr;
        bfr[0] = f2bf(b0[0]); bfr[1] = f2bf(b0[1]); bfr[2] = f2bf(b0[2]); bfr[3] = f2bf(b0[3]);
        bfr[4] = f2bf(b1[0]); bfr[5] = f2bf(b1[1]); bfr[6] = f2bf(b1[2]); bfr[7] = f2bf(b1[3]);
#pragma unroll
        for (int t2 = 0; t2 < 4; ++t2) {
            short8v lf = *reinterpret_cast<const short8v*>(
                &lnvT[(16 * t2 + li) * 96 + 8 * g + 32 * c]);
            racc[t2] = MFMA16(bfr, lf, racc[t2]);
        }
    }

    // write: C[q=4g+r][d=16t2+li]
#pragma unroll
    for (int t2 = 0; t2 < 4; ++t2)
#pragma unroll
        for (int r = 0; r < 4; ++r) {
            int row = q0 + 4 * g + r;
            outp[((size_t)b * SS + row) * HIDV + h * DD + 16 * t2 + li] =
                (oacc[t2][r] + racc[t2][r]) * invr[r];
        }
}

// ---------------- launcher ----------------
extern "C" void kernel_launch(void* const* d_in, const int* in_sizes, int n_in,
                              void* d_out, int out_size, void* d_ws, size_t ws_size,
                              hipStream_t stream) {
    const float* hidden = (const float*)d_in[0];
    const float* mask   = (const float*)d_in[1];
    const int*   arc    = (const int*)d_in[2];
    const float* Wq = (const float*)d_in[3];
    const float* bq = (const float*)d_in[4];
    const float* Wk = (const float*)d_in[5];
    const float* bk = (const float*)d_in[6];
    const float* Wv = (const float*)d_in[7];
    const float* bv = (const float*)d_in[8];
    const float* rel_k = (const float*)d_in[9];
    const float* rel_v = (const float*)d_in[10];
    const float* lng_k = (const float*)d_in[11];
    const float* lnb_k = (const float*)d_in[12];
    const float* lng_v = (const float*)d_in[13];
    const float* lnb_v = (const float*)d_in[14];
    float* out = (float*)d_out;

    char* p = (char*)d_ws;
    auto carve = [&](size_t bytes) { char* r = p; p += (bytes + 255) & ~(size_t)255; return r; };
    short* lnkb = (short*)carve((size_t)96 * DD * 2);
    short* lnvT = (short*)carve((size_t)DD * 96 * 2);
    short* hbf  = (short*)carve((size_t)BB * SS * HIDV * 2);
    short* WqT  = (short*)carve((size_t)HIDV * HIDV * 2);
    short* WkT  = (short*)carve((size_t)HIDV * HIDV * 2);
    short* WvT  = (short*)carve((size_t)HIDV * HIDV * 2);
    const size_t per = (size_t)BB * HH * SS * DD;
    short* qbuf = (short*)carve(per * 2);
    short* kbuf = (short*)carve(per * 2);
    short* vtb  = (short*)carve(per * 2);
    unsigned int* arcP = (unsigned int*)carve((size_t)BB * 128 * SS * 4);

    prep_ln_kernel<<<1, 256, 0, stream>>>(rel_k, rel_v, lng_k, lnb_k, lng_v, lnb_v, lnkb, lnvT);
    conv_hidden_kernel<<<(BB * SS * HIDV) / 1024, 256, 0, stream>>>(hidden, hbf);
    transw_kernel<<<dim3(24, 24, 3), 256, 0, stream>>>(Wq, Wk, Wv, WqT, WkT, WvT);
    arcpack_kernel<<<dim3(8, BB), 256, 0, stream>>>(arc, arcP);
    qkv_gemm_kernel<<<dim3(HIDV / 64, (BB * SS) / 64, 3), 256, 0, stream>>>(
        hbf, WqT, WkT, WvT, bq, bk, bv, qbuf, kbuf, vtb);
    attn_kernel<<<dim3(BB * HH * 8), 256, 0, stream>>>(
        qbuf, kbuf, vtb, arcP, mask, lnkb, lnvT, out);
}

// Round 17
// 192.068 us; speedup vs baseline: 1.0561x; 1.0206x over previous
//
#include <hip/hip_runtime.h>
#include <hip/hip_bf16.h>

#define BB 8
#define SS 512
#define HIDV 768
#define HH 12
#define DD 64
#define LV 81

typedef __attribute__((ext_vector_type(8))) short short8v;
typedef __attribute__((ext_vector_type(4))) short short4v;
typedef __attribute__((ext_vector_type(4))) float f32x4;

#define MFMA16(a, b, c) __builtin_amdgcn_mfma_f32_16x16x32_bf16(a, b, c, 0, 0, 0)

__device__ __forceinline__ short f2bf(float f) {
    __hip_bfloat16 h = __float2bfloat16(f);
    return *reinterpret_cast<short*>(&h);
}
__device__ __forceinline__ void gload16(const void* g, void* l) {
    __builtin_amdgcn_global_load_lds((const __attribute__((address_space(1))) void*)g,
                                     (__attribute__((address_space(3))) void*)l, 16, 0, 0);
}

// ---------------- prep_ln (LDS-free): lnkb bf16 [96][64], lnvT bf16 [64][96] ----------------
__global__ __launch_bounds__(256) void prep_ln_kernel(
    const float* __restrict__ rel_k, const float* __restrict__ rel_v,
    const float* __restrict__ gk, const float* __restrict__ bk,
    const float* __restrict__ gv, const float* __restrict__ bv,
    short* __restrict__ lnkb, short* __restrict__ lnvT) {
    int t = threadIdx.x;
    if (t < 192) {
        bool isv = (t >= 96);
        int r = isv ? t - 96 : t;
        if (r < LV) {
            const float* row = (isv ? rel_v : rel_k) + r * DD;
            const float* g = isv ? gv : gk;
            const float* be = isv ? bv : bk;
            float mu = 0.f;
            for (int d = 0; d < DD; ++d) mu += row[d];
            mu *= (1.f / DD);
            float var = 0.f;
            for (int d = 0; d < DD; ++d) { float x = row[d] - mu; var += x * x; }
            var *= (1.f / DD);
            float rs = rsqrtf(var + 1e-5f);
            if (!isv) {
                for (int d = 0; d < DD; ++d)
                    lnkb[r * DD + d] = f2bf((row[d] - mu) * rs * g[d] + be[d]);
            } else {
                for (int d = 0; d < DD; ++d)
                    lnvT[d * 96 + r] = f2bf((row[d] - mu) * rs * g[d] + be[d]);
            }
        } else {
            // zero-pad rows/cols 81..95
            if (!isv) for (int d = 0; d < DD; ++d) lnkb[r * DD + d] = 0;
            else      for (int d = 0; d < DD; ++d) lnvT[d * 96 + r] = 0;
        }
    }
}

// ---------------- fused prep: conv_hidden | transw | arcpack (range-switched) ----------------
#define NCONV 3072
#define NTRANS 1728
#define NARC 64
__global__ __launch_bounds__(256) void prep_fused_kernel(
    const float* __restrict__ hidden, short* __restrict__ hbf,
    const float* __restrict__ Wq, const float* __restrict__ Wk, const float* __restrict__ Wv,
    short* __restrict__ WqT, short* __restrict__ WkT, short* __restrict__ WvT,
    const int* __restrict__ arc, unsigned int* __restrict__ arcP) {
    __shared__ unsigned int sbuf[64 * 129];     // max of transw tile (32*33 f32) / arcpack tbuf
    const int bid = blockIdx.x;
    const int tid = threadIdx.x;

    if (bid < NCONV) {
        int i = (bid * 256 + tid) * 4;
        float4 v = *reinterpret_cast<const float4*>(&hidden[i]);
        short4v o; o[0] = f2bf(v.x); o[1] = f2bf(v.y); o[2] = f2bf(v.z); o[3] = f2bf(v.w);
        *reinterpret_cast<short4v*>(&hbf[i]) = o;
    } else if (bid < NCONV + NTRANS) {
        int e = bid - NCONV;
        int z = e / 576, rem = e - z * 576;
        int by = rem / 24, bxx = rem - by * 24;
        const float* W; short* O;
        if (z == 0) { W = Wq; O = WqT; }
        else if (z == 1) { W = Wk; O = WkT; }
        else { W = Wv; O = WvT; }
        float* tile = reinterpret_cast<float*>(sbuf);   // [32][33]
        int k0 = by * 32, n0 = bxx * 32;
        int r = tid >> 3, c4 = (tid & 7) * 4;
        float4 v = *reinterpret_cast<const float4*>(&W[(size_t)(k0 + r) * HIDV + n0 + c4]);
        tile[r * 33 + c4 + 0] = v.x; tile[r * 33 + c4 + 1] = v.y;
        tile[r * 33 + c4 + 2] = v.z; tile[r * 33 + c4 + 3] = v.w;
        __syncthreads();
        short4v o;
        o[0] = f2bf(tile[(c4 + 0) * 33 + r]); o[1] = f2bf(tile[(c4 + 1) * 33 + r]);
        o[2] = f2bf(tile[(c4 + 2) * 33 + r]); o[3] = f2bf(tile[(c4 + 3) * 33 + r]);
        *reinterpret_cast<short4v*>(&O[(size_t)(n0 + r) * HIDV + k0 + c4]) = o;
    } else {
        int e = bid - NCONV - NTRANS;
        int b = e >> 3, q0 = (e & 7) * 64;
        unsigned int* tbuf = sbuf;    // [64][129]
        for (int i = tid; i < 64 * 128; i += 256) {
            int r = i >> 7, c4 = i & 127;
            int4 v = *reinterpret_cast<const int4*>(
                &arc[((size_t)(b * SS) + q0 + r) * SS + 4 * c4]);
            tbuf[r * 129 + c4] = (unsigned)(v.x & 255) | ((unsigned)(v.y & 255) << 8) |
                                 ((unsigned)(v.z & 255) << 16) | ((unsigned)(v.w & 255) << 24);
        }
        __syncthreads();
        for (int i = tid; i < 128 * 64; i += 256) {
            int k4 = i >> 6, r = i & 63;
            arcP[((size_t)b * 128 + k4) * SS + q0 + r] = tbuf[r * 129 + k4];
        }
    }
}

// ---------------- QKV GEMM bf16 MFMA (64x64, proven) ----------------
__global__ __launch_bounds__(256) void qkv_gemm_kernel(
    const short* __restrict__ Abf,
    const short* __restrict__ WqT, const short* __restrict__ WkT, const short* __restrict__ WvT,
    const float* __restrict__ bq, const float* __restrict__ bk, const float* __restrict__ bv,
    short* __restrict__ qo, short* __restrict__ ko, short* __restrict__ vto) {
    const short* Bt; const float* bias;
    int z = blockIdx.z;
    if (z == 0) { Bt = WqT; bias = bq; }
    else if (z == 1) { Bt = WkT; bias = bk; }
    else { Bt = WvT; bias = bv; }

    __shared__ short smem[8192];
    short* As = smem;
    short* Bs = smem + 4096;

    const int tid = threadIdx.x;
    const int lane = tid & 63, w = tid >> 6;
    const int li = lane & 15, g = lane >> 4;
    const int wr = w >> 1, wc = w & 1;
    const int m0 = blockIdx.y * 64, n0 = blockIdx.x * 64;

    f32x4 acc[2][2];
    for (int ra = 0; ra < 2; ++ra)
        for (int cb = 0; cb < 2; ++cb)
            for (int r = 0; r < 4; ++r) acc[ra][cb][r] = 0.f;

#pragma unroll 1
    for (int k0 = 0; k0 < HIDV; k0 += 64) {
#pragma unroll
        for (int j = 0; j < 2; ++j) {
            int c = j * 256 + tid;
            int row = c >> 3, s = c & 7;
            int src = s ^ (row & 7);
            gload16(Abf + (size_t)(m0 + row) * HIDV + k0 + src * 8, As + c * 8);
            gload16(Bt + (size_t)(n0 + row) * HIDV + k0 + src * 8, Bs + c * 8);
        }
        __syncthreads();
#pragma unroll
        for (int c = 0; c < 2; ++c) {
            short8v af[2], bf[2];
#pragma unroll
            for (int ra = 0; ra < 2; ++ra) {
                int row = 32 * wr + 16 * ra + li;
                int chunk = (4 * c + g) ^ (row & 7);
                af[ra] = *reinterpret_cast<const short8v*>(&As[row * 64 + chunk * 8]);
            }
#pragma unroll
            for (int cb = 0; cb < 2; ++cb) {
                int rowb = 32 * wc + 16 * cb + li;
                int chunk = (4 * c + g) ^ (rowb & 7);
                bf[cb] = *reinterpret_cast<const short8v*>(&Bs[rowb * 64 + chunk * 8]);
            }
#pragma unroll
            for (int ra = 0; ra < 2; ++ra)
#pragma unroll
                for (int cb = 0; cb < 2; ++cb)
                    acc[ra][cb] = MFMA16(af[ra], bf[cb], acc[ra][cb]);
        }
        __syncthreads();
    }

    const int h = n0 >> 6;
    const int bidx = m0 >> 9;
    if (z < 2) {
        short* dst = (z == 0) ? qo : ko;
        float sc = (z == 0) ? 1.f : 0.125f;
#pragma unroll
        for (int ra = 0; ra < 2; ++ra)
#pragma unroll
            for (int cb = 0; cb < 2; ++cb) {
                int n = 32 * wc + 16 * cb + li;
                float bv_ = bias[n0 + n];
#pragma unroll
                for (int r = 0; r < 4; ++r) {
                    int m = m0 + 32 * wr + 16 * ra + 4 * g + r;
                    int s = m & 511;
                    dst[(((size_t)bidx * HH + h) * SS + s) * DD + n] =
                        f2bf((acc[ra][cb][r] + bv_) * sc);
                }
            }
    } else {
        short* Cs = smem;
#pragma unroll
        for (int ra = 0; ra < 2; ++ra)
#pragma unroll
            for (int cb = 0; cb < 2; ++cb) {
                int nl = 32 * wc + 16 * cb + li;
                float bv_ = bias[n0 + nl];
#pragma unroll
                for (int r = 0; r < 4; ++r) {
                    int ml = 32 * wr + 16 * ra + 4 * g + r;
                    Cs[nl * 72 + ml] = f2bf(acc[ra][cb][r] + bv_);
                }
            }
        __syncthreads();
        for (int c = tid; c < 512; c += 256) {
            int dl = c >> 3, s8 = (c & 7) * 8;
            short8v vv = *reinterpret_cast<const short8v*>(&Cs[dl * 72 + s8]);
            *reinterpret_cast<short8v*>(
                &vto[(((size_t)bidx * HH + h) * DD + dl) * SS + (m0 & 511) + s8]) = vv;
        }
    }
}

// ---------------- fused attention (r16 + V prefetched in phase 2) ----------------
__global__ __launch_bounds__(256, 2) void attn_kernel(
    const short* __restrict__ qb, const short* __restrict__ kb, const short* __restrict__ vt,
    const unsigned int* __restrict__ arcP, const float* __restrict__ maskp,
    const short* __restrict__ lnkb, const short* __restrict__ lnvT,
    float* __restrict__ outp) {
    __shared__ float qlds[4][16][84];
    __shared__ float bucket[4][16][100];

    const int tid = threadIdx.x;
    const int w = tid >> 6, lane = tid & 63;
    const int li = lane & 15, g = lane >> 4;
    const int bx = blockIdx.x;
    const int b = bx & 7;
    const int rest = bx >> 3;
    const int h = rest % HH, qt = rest / HH;
    const int bh = b * HH + h;
    const int q0 = qt * 64 + w * 16;

    const short* kbp = kb + (size_t)bh * SS * DD;
    const short* vbp = vt + (size_t)bh * DD * SS;
    const unsigned int* apb = arcP + (size_t)b * 128 * SS;
    const float* mkb = maskp + (size_t)b * SS;

    for (int i = lane; i < 16 * 100; i += 64) (&bucket[w][0][0])[i] = 0.f;

    short8v qf0, qf1;
    {
        const short* qrow = qb + ((size_t)bh * SS + q0 + li) * DD + 8 * g;
        qf0 = *reinterpret_cast<const short8v*>(qrow);
        qf1 = *reinterpret_cast<const short8v*>(qrow + 32);
    }

    // qrel tile via MFMA (wave-private, f32 LDS)
#pragma unroll
    for (int ct = 0; ct < 6; ++ct) {
        f32x4 a = {0.f, 0.f, 0.f, 0.f};
        short8v b0 = *reinterpret_cast<const short8v*>(&lnkb[(16 * ct + li) * DD + 8 * g]);
        short8v b1 = *reinterpret_cast<const short8v*>(&lnkb[(16 * ct + li) * DD + 32 + 8 * g]);
        a = MFMA16(qf0, b0, a);
        a = MFMA16(qf1, b1, a);
        if (16 * ct + li < 84)
#pragma unroll
            for (int r = 0; r < 4; ++r) qlds[w][4 * g + r][16 * ct + li] = a[r];
    }

    f32x4 oacc[4];
    for (int t = 0; t < 4; ++t) for (int r = 0; r < 4; ++r) oacc[t][r] = 0.f;

    // pipeline state
    short8v kf[8];
    short4v vreg[16];          // V(kt), loaded phase 2, consumed phase 5
    unsigned int a_[2][4];
    float4 m_[2][4];
    float qv_[2][16];
#pragma unroll
    for (int t = 0; t < 4; ++t) {
        const short* kr = kbp + (size_t)(16 * t + li) * DD + 8 * g;
        kf[2 * t] = *reinterpret_cast<const short8v*>(kr);
        kf[2 * t + 1] = *reinterpret_cast<const short8v*>(kr + 32);
        a_[0][t] = apb[(size_t)(4 * t + g) * SS + q0 + li];
        m_[0][t] = *reinterpret_cast<const float4*>(&mkb[16 * t + 4 * g]);
    }
#pragma unroll
    for (int t = 0; t < 4; ++t) {
        const unsigned int a4 = a_[0][t];
        qv_[0][4 * t + 0] = qlds[w][li][a4 & 255];
        qv_[0][4 * t + 1] = qlds[w][li][(a4 >> 8) & 255];
        qv_[0][4 * t + 2] = qlds[w][li][(a4 >> 16) & 255];
        qv_[0][4 * t + 3] = qlds[w][li][a4 >> 24];
    }

#pragma unroll
    for (int kt = 0; kt < 8; ++kt) {
        const int cur = kt & 1, nxt = cur ^ 1;
        const int kb0 = kt * 64;

        // 1. QK^T (K pre-scaled 0.125); C[k=16t+4g+r][q=li]
        f32x4 sacc[4];
#pragma unroll
        for (int t = 0; t < 4; ++t) {
            f32x4 a = {0.f, 0.f, 0.f, 0.f};
            a = MFMA16(kf[2 * t], qf0, a);
            a = MFMA16(kf[2 * t + 1], qf1, a);
            sacc[t] = a;
        }

        // 2. issue V(kt), then next tile's K/arc/mask, then gather next qrel values
#pragma unroll
        for (int dt = 0; dt < 2; ++dt)
#pragma unroll
            for (int t2 = 0; t2 < 4; ++t2) {
                const short* vr = vbp + (size_t)(16 * t2 + li) * SS + kb0 + 32 * dt + 4 * g;
                vreg[8 * dt + 2 * t2 + 0] = *reinterpret_cast<const short4v*>(vr);
                vreg[8 * dt + 2 * t2 + 1] = *reinterpret_cast<const short4v*>(vr + 16);
            }
        if (kt < 7) {
#pragma unroll
            for (int t = 0; t < 4; ++t) {
                const short* kr = kbp + (size_t)(kb0 + 64 + 16 * t + li) * DD + 8 * g;
                kf[2 * t] = *reinterpret_cast<const short8v*>(kr);
                kf[2 * t + 1] = *reinterpret_cast<const short8v*>(kr + 32);
                a_[nxt][t] = apb[(size_t)((kt + 1) * 16 + 4 * t + g) * SS + q0 + li];
                m_[nxt][t] = *reinterpret_cast<const float4*>(&mkb[kb0 + 64 + 16 * t + 4 * g]);
            }
#pragma unroll
            for (int t = 0; t < 4; ++t) {
                const unsigned int a4 = a_[nxt][t];
                qv_[nxt][4 * t + 0] = qlds[w][li][a4 & 255];
                qv_[nxt][4 * t + 1] = qlds[w][li][(a4 >> 8) & 255];
                qv_[nxt][4 * t + 2] = qlds[w][li][(a4 >> 16) & 255];
                qv_[nxt][4 * t + 3] = qlds[w][li][a4 >> 24];
            }
        }

        // 3. exp from registers only
        float p[16];
#pragma unroll
        for (int t = 0; t < 4; ++t) {
            p[4 * t + 0] = __expf(sacc[t][0] + qv_[cur][4 * t + 0] + m_[cur][t].x);
            p[4 * t + 1] = __expf(sacc[t][1] + qv_[cur][4 * t + 1] + m_[cur][t].y);
            p[4 * t + 2] = __expf(sacc[t][2] + qv_[cur][4 * t + 2] + m_[cur][t].z);
            p[4 * t + 3] = __expf(sacc[t][3] + qv_[cur][4 * t + 3] + m_[cur][t].w);
        }

        // 4. HW LDS atomics
#pragma unroll
        for (int t = 0; t < 4; ++t) {
            const unsigned int a4 = a_[cur][t];
            unsafeAtomicAdd(&bucket[w][li][a4 & 255], p[4 * t + 0]);
            unsafeAtomicAdd(&bucket[w][li][(a4 >> 8) & 255], p[4 * t + 1]);
            unsafeAtomicAdd(&bucket[w][li][(a4 >> 16) & 255], p[4 * t + 2]);
            unsafeAtomicAdd(&bucket[w][li][a4 >> 24], p[4 * t + 3]);
        }

        // 5. pack P and PV (vreg loaded in phase 2)
        short8v pfrag[2];
#pragma unroll
        for (int t = 0; t < 4; ++t)
#pragma unroll
            for (int r = 0; r < 4; ++r) pfrag[t >> 1][4 * (t & 1) + r] = f2bf(p[4 * t + r]);
#pragma unroll
        for (int dt = 0; dt < 2; ++dt) {
#pragma unroll
            for (int t2 = 0; t2 < 4; ++t2) {
                short4v v0 = vreg[8 * dt + 2 * t2 + 0];
                short4v v1 = vreg[8 * dt + 2 * t2 + 1];
                short8v vf;
                vf[0] = v0[0]; vf[1] = v0[1]; vf[2] = v0[2]; vf[3] = v0[3];
                vf[4] = v1[0]; vf[5] = v1[1]; vf[6] = v1[2]; vf[7] = v1[3];
                oacc[t2] = MFMA16(pfrag[dt], vf, oacc[t2]);
            }
        }
    }

    // rowsum for q=li from buckets
    float lsum = 0.f;
#pragma unroll
    for (int j = 0; j < 24; ++j) {
        int c = 24 * g + j;
        lsum += (c < 81) ? bucket[w][li][c] : 0.f;
    }
    lsum += __shfl_xor(lsum, 16);
    lsum += __shfl_xor(lsum, 32);
    float inv = 1.f / lsum;
    float invr[4];
#pragma unroll
    for (int r = 0; r < 4; ++r) invr[r] = __shfl(inv, 4 * g + r);

    // rel-V: racc = bucket @ lnvT (labels zero-padded to 96)
    f32x4 racc[4];
    for (int t = 0; t < 4; ++t) for (int r = 0; r < 4; ++r) racc[t][r] = 0.f;
#pragma unroll
    for (int c = 0; c < 3; ++c) {
        f32x4 b0 = *reinterpret_cast<const f32x4*>(&bucket[w][li][8 * g + 32 * c]);
        f32x4 b1 = *reinterpret_cast<const f32x4*>(&bucket[w][li][8 * g + 32 * c + 4]);
        short8v bfr;
        bfr[0] = f2bf(b0[0]); bfr[1] = f2bf(b0[1]); bfr[2] = f2bf(b0[2]); bfr[3] = f2bf(b0[3]);
        bfr[4] = f2bf(b1[0]); bfr[5] = f2bf(b1[1]); bfr[6] = f2bf(b1[2]); bfr[7] = f2bf(b1[3]);
#pragma unroll
        for (int t2 = 0; t2 < 4; ++t2) {
            short8v lf = *reinterpret_cast<const short8v*>(
                &lnvT[(16 * t2 + li) * 96 + 8 * g + 32 * c]);
            racc[t2] = MFMA16(bfr, lf, racc[t2]);
        }
    }

    // write: C[q=4g+r][d=16t2+li]
#pragma unroll
    for (int t2 = 0; t2 < 4; ++t2)
#pragma unroll
        for (int r = 0; r < 4; ++r) {
            int row = q0 + 4 * g + r;
            outp[((size_t)b * SS + row) * HIDV + h * DD + 16 * t2 + li] =
                (oacc[t2][r] + racc[t2][r]) * invr[r];
        }
}

// ---------------- launcher ----------------
extern "C" void kernel_launch(void* const* d_in, const int* in_sizes, int n_in,
                              void* d_out, int out_size, void* d_ws, size_t ws_size,
                              hipStream_t stream) {
    const float* hidden = (const float*)d_in[0];
    const float* mask   = (const float*)d_in[1];
    const int*   arc    = (const int*)d_in[2];
    const float* Wq = (const float*)d_in[3];
    const float* bq = (const float*)d_in[4];
    const float* Wk = (const float*)d_in[5];
    const float* bk = (const float*)d_in[6];
    const float* Wv = (const float*)d_in[7];
    const float* bv = (const float*)d_in[8];
    const float* rel_k = (const float*)d_in[9];
    const float* rel_v = (const float*)d_in[10];
    const float* lng_k = (const float*)d_in[11];
    const float* lnb_k = (const float*)d_in[12];
    const float* lng_v = (const float*)d_in[13];
    const float* lnb_v = (const float*)d_in[14];
    float* out = (float*)d_out;

    char* p = (char*)d_ws;
    auto carve = [&](size_t bytes) { char* r = p; p += (bytes + 255) & ~(size_t)255; return r; };
    short* lnkb = (short*)carve((size_t)96 * DD * 2);
    short* lnvT = (short*)carve((size_t)DD * 96 * 2);
    short* hbf  = (short*)carve((size_t)BB * SS * HIDV * 2);
    short* WqT  = (short*)carve((size_t)HIDV * HIDV * 2);
    short* WkT  = (short*)carve((size_t)HIDV * HIDV * 2);
    short* WvT  = (short*)carve((size_t)HIDV * HIDV * 2);
    const size_t per = (size_t)BB * HH * SS * DD;
    short* qbuf = (short*)carve(per * 2);
    short* kbuf = (short*)carve(per * 2);
    short* vtb  = (short*)carve(per * 2);
    unsigned int* arcP = (unsigned int*)carve((size_t)BB * 128 * SS * 4);

    prep_ln_kernel<<<1, 256, 0, stream>>>(rel_k, rel_v, lng_k, lnb_k, lng_v, lnb_v, lnkb, lnvT);
    prep_fused_kernel<<<dim3(NCONV + NTRANS + NARC), 256, 0, stream>>>(
        hidden, hbf, Wq, Wk, Wv, WqT, WkT, WvT, arc, arcP);
    qkv_gemm_kernel<<<dim3(HIDV / 64, (BB * SS) / 64, 3), 256, 0, stream>>>(
        hbf, WqT, WkT, WvT, bq, bk, bv, qbuf, kbuf, vtb);
    attn_kernel<<<dim3(BB * HH * 8), 256, 0, stream>>>(
        qbuf, kbuf, vtb, arcP, mask, lnkb, lnvT, out);
}

// Round 18
// 191.883 us; speedup vs baseline: 1.0571x; 1.0010x over previous
//
#include <hip/hip_runtime.h>
#include <hip/hip_bf16.h>

#define BB 8
#define SS 512
#define HIDV 768
#define HH 12
#define DD 64
#define LV 81

typedef __attribute__((ext_vector_type(8))) short short8v;
typedef __attribute__((ext_vector_type(4))) short short4v;
typedef __attribute__((ext_vector_type(4))) float f32x4;

#define MFMA16(a, b, c) __builtin_amdgcn_mfma_f32_16x16x32_bf16(a, b, c, 0, 0, 0)

__device__ __forceinline__ short f2bf(float f) {
    __hip_bfloat16 h = __float2bfloat16(f);
    return *reinterpret_cast<short*>(&h);
}
__device__ __forceinline__ void gload16(const void* g, void* l) {
    __builtin_amdgcn_global_load_lds((const __attribute__((address_space(1))) void*)g,
                                     (__attribute__((address_space(3))) void*)l, 16, 0, 0);
}
// Guaranteed LDS-pipe fire-and-forget float atomic: ds_add_f32 on an explicit
// addrspace(3) pointer. No return value, no vmcnt involvement.
__device__ __forceinline__ void ldsAddAsm(float* p, float v) {
    __attribute__((address_space(3))) float* lp =
        (__attribute__((address_space(3))) float*)p;
    asm volatile("ds_add_f32 %0, %1" : : "v"(lp), "v"(v) : "memory");
}

// ---------------- prep_ln (LDS-free): lnkb bf16 [96][64], lnvT bf16 [64][96] ----------------
__global__ __launch_bounds__(256) void prep_ln_kernel(
    const float* __restrict__ rel_k, const float* __restrict__ rel_v,
    const float* __restrict__ gk, const float* __restrict__ bk,
    const float* __restrict__ gv, const float* __restrict__ bv,
    short* __restrict__ lnkb, short* __restrict__ lnvT) {
    int t = threadIdx.x;
    if (t < 192) {
        bool isv = (t >= 96);
        int r = isv ? t - 96 : t;
        if (r < LV) {
            const float* row = (isv ? rel_v : rel_k) + r * DD;
            const float* g = isv ? gv : gk;
            const float* be = isv ? bv : bk;
            float mu = 0.f;
            for (int d = 0; d < DD; ++d) mu += row[d];
            mu *= (1.f / DD);
            float var = 0.f;
            for (int d = 0; d < DD; ++d) { float x = row[d] - mu; var += x * x; }
            var *= (1.f / DD);
            float rs = rsqrtf(var + 1e-5f);
            if (!isv) {
                for (int d = 0; d < DD; ++d)
                    lnkb[r * DD + d] = f2bf((row[d] - mu) * rs * g[d] + be[d]);
            } else {
                for (int d = 0; d < DD; ++d)
                    lnvT[d * 96 + r] = f2bf((row[d] - mu) * rs * g[d] + be[d]);
            }
        } else {
            if (!isv) for (int d = 0; d < DD; ++d) lnkb[r * DD + d] = 0;
            else      for (int d = 0; d < DD; ++d) lnvT[d * 96 + r] = 0;
        }
    }
}

// ---------------- fused prep: conv_hidden | transw | arcpack (range-switched) ----------------
#define NCONV 3072
#define NTRANS 1728
#define NARC 64
__global__ __launch_bounds__(256) void prep_fused_kernel(
    const float* __restrict__ hidden, short* __restrict__ hbf,
    const float* __restrict__ Wq, const float* __restrict__ Wk, const float* __restrict__ Wv,
    short* __restrict__ WqT, short* __restrict__ WkT, short* __restrict__ WvT,
    const int* __restrict__ arc, unsigned int* __restrict__ arcP) {
    __shared__ unsigned int sbuf[64 * 129];
    const int bid = blockIdx.x;
    const int tid = threadIdx.x;

    if (bid < NCONV) {
        int i = (bid * 256 + tid) * 4;
        float4 v = *reinterpret_cast<const float4*>(&hidden[i]);
        short4v o; o[0] = f2bf(v.x); o[1] = f2bf(v.y); o[2] = f2bf(v.z); o[3] = f2bf(v.w);
        *reinterpret_cast<short4v*>(&hbf[i]) = o;
    } else if (bid < NCONV + NTRANS) {
        int e = bid - NCONV;
        int z = e / 576, rem = e - z * 576;
        int by = rem / 24, bxx = rem - by * 24;
        const float* W; short* O;
        if (z == 0) { W = Wq; O = WqT; }
        else if (z == 1) { W = Wk; O = WkT; }
        else { W = Wv; O = WvT; }
        float* tile = reinterpret_cast<float*>(sbuf);   // [32][33]
        int k0 = by * 32, n0 = bxx * 32;
        int r = tid >> 3, c4 = (tid & 7) * 4;
        float4 v = *reinterpret_cast<const float4*>(&W[(size_t)(k0 + r) * HIDV + n0 + c4]);
        tile[r * 33 + c4 + 0] = v.x; tile[r * 33 + c4 + 1] = v.y;
        tile[r * 33 + c4 + 2] = v.z; tile[r * 33 + c4 + 3] = v.w;
        __syncthreads();
        short4v o;
        o[0] = f2bf(tile[(c4 + 0) * 33 + r]); o[1] = f2bf(tile[(c4 + 1) * 33 + r]);
        o[2] = f2bf(tile[(c4 + 2) * 33 + r]); o[3] = f2bf(tile[(c4 + 3) * 33 + r]);
        *reinterpret_cast<short4v*>(&O[(size_t)(n0 + r) * HIDV + k0 + c4]) = o;
    } else {
        int e = bid - NCONV - NTRANS;
        int b = e >> 3, q0 = (e & 7) * 64;
        unsigned int* tbuf = sbuf;    // [64][129]
        for (int i = tid; i < 64 * 128; i += 256) {
            int r = i >> 7, c4 = i & 127;
            int4 v = *reinterpret_cast<const int4*>(
                &arc[((size_t)(b * SS) + q0 + r) * SS + 4 * c4]);
            tbuf[r * 129 + c4] = (unsigned)(v.x & 255) | ((unsigned)(v.y & 255) << 8) |
                                 ((unsigned)(v.z & 255) << 16) | ((unsigned)(v.w & 255) << 24);
        }
        __syncthreads();
        for (int i = tid; i < 128 * 64; i += 256) {
            int k4 = i >> 6, r = i & 63;
            arcP[((size_t)b * 128 + k4) * SS + q0 + r] = tbuf[r * 129 + k4];
        }
    }
}

// ---------------- QKV GEMM bf16 MFMA (64x64, proven) ----------------
__global__ __launch_bounds__(256) void qkv_gemm_kernel(
    const short* __restrict__ Abf,
    const short* __restrict__ WqT, const short* __restrict__ WkT, const short* __restrict__ WvT,
    const float* __restrict__ bq, const float* __restrict__ bk, const float* __restrict__ bv,
    short* __restrict__ qo, short* __restrict__ ko, short* __restrict__ vto) {
    const short* Bt; const float* bias;
    int z = blockIdx.z;
    if (z == 0) { Bt = WqT; bias = bq; }
    else if (z == 1) { Bt = WkT; bias = bk; }
    else { Bt = WvT; bias = bv; }

    __shared__ short smem[8192];
    short* As = smem;
    short* Bs = smem + 4096;

    const int tid = threadIdx.x;
    const int lane = tid & 63, w = tid >> 6;
    const int li = lane & 15, g = lane >> 4;
    const int wr = w >> 1, wc = w & 1;
    const int m0 = blockIdx.y * 64, n0 = blockIdx.x * 64;

    f32x4 acc[2][2];
    for (int ra = 0; ra < 2; ++ra)
        for (int cb = 0; cb < 2; ++cb)
            for (int r = 0; r < 4; ++r) acc[ra][cb][r] = 0.f;

#pragma unroll 1
    for (int k0 = 0; k0 < HIDV; k0 += 64) {
#pragma unroll
        for (int j = 0; j < 2; ++j) {
            int c = j * 256 + tid;
            int row = c >> 3, s = c & 7;
            int src = s ^ (row & 7);
            gload16(Abf + (size_t)(m0 + row) * HIDV + k0 + src * 8, As + c * 8);
            gload16(Bt + (size_t)(n0 + row) * HIDV + k0 + src * 8, Bs + c * 8);
        }
        __syncthreads();
#pragma unroll
        for (int c = 0; c < 2; ++c) {
            short8v af[2], bf[2];
#pragma unroll
            for (int ra = 0; ra < 2; ++ra) {
                int row = 32 * wr + 16 * ra + li;
                int chunk = (4 * c + g) ^ (row & 7);
                af[ra] = *reinterpret_cast<const short8v*>(&As[row * 64 + chunk * 8]);
            }
#pragma unroll
            for (int cb = 0; cb < 2; ++cb) {
                int rowb = 32 * wc + 16 * cb + li;
                int chunk = (4 * c + g) ^ (rowb & 7);
                bf[cb] = *reinterpret_cast<const short8v*>(&Bs[rowb * 64 + chunk * 8]);
            }
#pragma unroll
            for (int ra = 0; ra < 2; ++ra)
#pragma unroll
                for (int cb = 0; cb < 2; ++cb)
                    acc[ra][cb] = MFMA16(af[ra], bf[cb], acc[ra][cb]);
        }
        __syncthreads();
    }

    const int h = n0 >> 6;
    const int bidx = m0 >> 9;
    if (z < 2) {
        short* dst = (z == 0) ? qo : ko;
        float sc = (z == 0) ? 1.f : 0.125f;
#pragma unroll
        for (int ra = 0; ra < 2; ++ra)
#pragma unroll
            for (int cb = 0; cb < 2; ++cb) {
                int n = 32 * wc + 16 * cb + li;
                float bv_ = bias[n0 + n];
#pragma unroll
                for (int r = 0; r < 4; ++r) {
                    int m = m0 + 32 * wr + 16 * ra + 4 * g + r;
                    int s = m & 511;
                    dst[(((size_t)bidx * HH + h) * SS + s) * DD + n] =
                        f2bf((acc[ra][cb][r] + bv_) * sc);
                }
            }
    } else {
        short* Cs = smem;
#pragma unroll
        for (int ra = 0; ra < 2; ++ra)
#pragma unroll
            for (int cb = 0; cb < 2; ++cb) {
                int nl = 32 * wc + 16 * cb + li;
                float bv_ = bias[n0 + nl];
#pragma unroll
                for (int r = 0; r < 4; ++r) {
                    int ml = 32 * wr + 16 * ra + 4 * g + r;
                    Cs[nl * 72 + ml] = f2bf(acc[ra][cb][r] + bv_);
                }
            }
        __syncthreads();
        for (int c = tid; c < 512; c += 256) {
            int dl = c >> 3, s8 = (c & 7) * 8;
            short8v vv = *reinterpret_cast<const short8v*>(&Cs[dl * 72 + s8]);
            *reinterpret_cast<short8v*>(
                &vto[(((size_t)bidx * HH + h) * DD + dl) * SS + (m0 & 511) + s8]) = vv;
        }
    }
}

// ---------------- fused attention (r17 + asm ds_add_f32 buckets) ----------------
__global__ __launch_bounds__(256, 2) void attn_kernel(
    const short* __restrict__ qb, const short* __restrict__ kb, const short* __restrict__ vt,
    const unsigned int* __restrict__ arcP, const float* __restrict__ maskp,
    const short* __restrict__ lnkb, const short* __restrict__ lnvT,
    float* __restrict__ outp) {
    __shared__ float qlds[4][16][84];
    __shared__ float bucket[4][16][100];

    const int tid = threadIdx.x;
    const int w = tid >> 6, lane = tid & 63;
    const int li = lane & 15, g = lane >> 4;
    const int bx = blockIdx.x;
    const int b = bx & 7;
    const int rest = bx >> 3;
    const int h = rest % HH, qt = rest / HH;
    const int bh = b * HH + h;
    const int q0 = qt * 64 + w * 16;

    const short* kbp = kb + (size_t)bh * SS * DD;
    const short* vbp = vt + (size_t)bh * DD * SS;
    const unsigned int* apb = arcP + (size_t)b * 128 * SS;
    const float* mkb = maskp + (size_t)b * SS;

    for (int i = lane; i < 16 * 100; i += 64) (&bucket[w][0][0])[i] = 0.f;

    short8v qf0, qf1;
    {
        const short* qrow = qb + ((size_t)bh * SS + q0 + li) * DD + 8 * g;
        qf0 = *reinterpret_cast<const short8v*>(qrow);
        qf1 = *reinterpret_cast<const short8v*>(qrow + 32);
    }

    // qrel tile via MFMA (wave-private, f32 LDS)
#pragma unroll
    for (int ct = 0; ct < 6; ++ct) {
        f32x4 a = {0.f, 0.f, 0.f, 0.f};
        short8v b0 = *reinterpret_cast<const short8v*>(&lnkb[(16 * ct + li) * DD + 8 * g]);
        short8v b1 = *reinterpret_cast<const short8v*>(&lnkb[(16 * ct + li) * DD + 32 + 8 * g]);
        a = MFMA16(qf0, b0, a);
        a = MFMA16(qf1, b1, a);
        if (16 * ct + li < 84)
#pragma unroll
            for (int r = 0; r < 4; ++r) qlds[w][4 * g + r][16 * ct + li] = a[r];
    }

    f32x4 oacc[4];
    for (int t = 0; t < 4; ++t) for (int r = 0; r < 4; ++r) oacc[t][r] = 0.f;

    // pipeline state
    short8v kf[8];
    short4v vreg[16];
    unsigned int a_[2][4];
    float4 m_[2][4];
    float qv_[2][16];
#pragma unroll
    for (int t = 0; t < 4; ++t) {
        const short* kr = kbp + (size_t)(16 * t + li) * DD + 8 * g;
        kf[2 * t] = *reinterpret_cast<const short8v*>(kr);
        kf[2 * t + 1] = *reinterpret_cast<const short8v*>(kr + 32);
        a_[0][t] = apb[(size_t)(4 * t + g) * SS + q0 + li];
        m_[0][t] = *reinterpret_cast<const float4*>(&mkb[16 * t + 4 * g]);
    }
#pragma unroll
    for (int t = 0; t < 4; ++t) {
        const unsigned int a4 = a_[0][t];
        qv_[0][4 * t + 0] = qlds[w][li][a4 & 255];
        qv_[0][4 * t + 1] = qlds[w][li][(a4 >> 8) & 255];
        qv_[0][4 * t + 2] = qlds[w][li][(a4 >> 16) & 255];
        qv_[0][4 * t + 3] = qlds[w][li][a4 >> 24];
    }

#pragma unroll
    for (int kt = 0; kt < 8; ++kt) {
        const int cur = kt & 1, nxt = cur ^ 1;
        const int kb0 = kt * 64;

        // 1. QK^T (K pre-scaled 0.125); C[k=16t+4g+r][q=li]
        f32x4 sacc[4];
#pragma unroll
        for (int t = 0; t < 4; ++t) {
            f32x4 a = {0.f, 0.f, 0.f, 0.f};
            a = MFMA16(kf[2 * t], qf0, a);
            a = MFMA16(kf[2 * t + 1], qf1, a);
            sacc[t] = a;
        }

        // 2. issue V(kt), next tile's K/arc/mask, gather next qrel values
#pragma unroll
        for (int dt = 0; dt < 2; ++dt)
#pragma unroll
            for (int t2 = 0; t2 < 4; ++t2) {
                const short* vr = vbp + (size_t)(16 * t2 + li) * SS + kb0 + 32 * dt + 4 * g;
                vreg[8 * dt + 2 * t2 + 0] = *reinterpret_cast<const short4v*>(vr);
                vreg[8 * dt + 2 * t2 + 1] = *reinterpret_cast<const short4v*>(vr + 16);
            }
        if (kt < 7) {
#pragma unroll
            for (int t = 0; t < 4; ++t) {
                const short* kr = kbp + (size_t)(kb0 + 64 + 16 * t + li) * DD + 8 * g;
                kf[2 * t] = *reinterpret_cast<const short8v*>(kr);
                kf[2 * t + 1] = *reinterpret_cast<const short8v*>(kr + 32);
                a_[nxt][t] = apb[(size_t)((kt + 1) * 16 + 4 * t + g) * SS + q0 + li];
                m_[nxt][t] = *reinterpret_cast<const float4*>(&mkb[kb0 + 64 + 16 * t + 4 * g]);
            }
#pragma unroll
            for (int t = 0; t < 4; ++t) {
                const unsigned int a4 = a_[nxt][t];
                qv_[nxt][4 * t + 0] = qlds[w][li][a4 & 255];
                qv_[nxt][4 * t + 1] = qlds[w][li][(a4 >> 8) & 255];
                qv_[nxt][4 * t + 2] = qlds[w][li][(a4 >> 16) & 255];
                qv_[nxt][4 * t + 3] = qlds[w][li][a4 >> 24];
            }
        }

        // 3. exp from registers only
        float p[16];
#pragma unroll
        for (int t = 0; t < 4; ++t) {
            p[4 * t + 0] = __expf(sacc[t][0] + qv_[cur][4 * t + 0] + m_[cur][t].x);
            p[4 * t + 1] = __expf(sacc[t][1] + qv_[cur][4 * t + 1] + m_[cur][t].y);
            p[4 * t + 2] = __expf(sacc[t][2] + qv_[cur][4 * t + 2] + m_[cur][t].z);
            p[4 * t + 3] = __expf(sacc[t][3] + qv_[cur][4 * t + 3] + m_[cur][t].w);
        }

        // 4. guaranteed ds_add_f32 (fire-and-forget, LDS pipe)
#pragma unroll
        for (int t = 0; t < 4; ++t) {
            const unsigned int a4 = a_[cur][t];
            ldsAddAsm(&bucket[w][li][a4 & 255], p[4 * t + 0]);
            ldsAddAsm(&bucket[w][li][(a4 >> 8) & 255], p[4 * t + 1]);
            ldsAddAsm(&bucket[w][li][(a4 >> 16) & 255], p[4 * t + 2]);
            ldsAddAsm(&bucket[w][li][a4 >> 24], p[4 * t + 3]);
        }

        // 5. pack P and PV
        short8v pfrag[2];
#pragma unroll
        for (int t = 0; t < 4; ++t)
#pragma unroll
            for (int r = 0; r < 4; ++r) pfrag[t >> 1][4 * (t & 1) + r] = f2bf(p[4 * t + r]);
#pragma unroll
        for (int dt = 0; dt < 2; ++dt) {
#pragma unroll
            for (int t2 = 0; t2 < 4; ++t2) {
                short4v v0 = vreg[8 * dt + 2 * t2 + 0];
                short4v v1 = vreg[8 * dt + 2 * t2 + 1];
                short8v vf;
                vf[0] = v0[0]; vf[1] = v0[1]; vf[2] = v0[2]; vf[3] = v0[3];
                vf[4] = v1[0]; vf[5] = v1[1]; vf[6] = v1[2]; vf[7] = v1[3];
                oacc[t2] = MFMA16(pfrag[dt], vf, oacc[t2]);
            }
        }
    }

    // rowsum for q=li from buckets (same-wave DS in-order: adds retired before reads)
    float lsum = 0.f;
#pragma unroll
    for (int j = 0; j < 24; ++j) {
        int c = 24 * g + j;
        lsum += (c < 81) ? bucket[w][li][c] : 0.f;
    }
    lsum += __shfl_xor(lsum, 16);
    lsum += __shfl_xor(lsum, 32);
    float inv = 1.f / lsum;
    float invr[4];
#pragma unroll
    for (int r = 0; r < 4; ++r) invr[r] = __shfl(inv, 4 * g + r);

    // rel-V: racc = bucket @ lnvT (labels zero-padded to 96)
    f32x4 racc[4];
    for (int t = 0; t < 4; ++t) for (int r = 0; r < 4; ++r) racc[t][r] = 0.f;
#pragma unroll
    for (int c = 0; c < 3; ++c) {
        f32x4 b0 = *reinterpret_cast<const f32x4*>(&bucket[w][li][8 * g + 32 * c]);
        f32x4 b1 = *reinterpret_cast<const f32x4*>(&bucket[w][li][8 * g + 32 * c + 4]);
        short8v bfr;
        bfr[0] = f2bf(b0[0]); bfr[1] = f2bf(b0[1]); bfr[2] = f2bf(b0[2]); bfr[3] = f2bf(b0[3]);
        bfr[4] = f2bf(b1[0]); bfr[5] = f2bf(b1[1]); bfr[6] = f2bf(b1[2]); bfr[7] = f2bf(b1[3]);
#pragma unroll
        for (int t2 = 0; t2 < 4; ++t2) {
            short8v lf = *reinterpret_cast<const short8v*>(
                &lnvT[(16 * t2 + li) * 96 + 8 * g + 32 * c]);
            racc[t2] = MFMA16(bfr, lf, racc[t2]);
        }
    }

    // write: C[q=4g+r][d=16t2+li]
#pragma unroll
    for (int t2 = 0; t2 < 4; ++t2)
#pragma unroll
        for (int r = 0; r < 4; ++r) {
            int row = q0 + 4 * g + r;
            outp[((size_t)b * SS + row) * HIDV + h * DD + 16 * t2 + li] =
                (oacc[t2][r] + racc[t2][r]) * invr[r];
        }
}

// ---------------- launcher ----------------
extern "C" void kernel_launch(void* const* d_in, const int* in_sizes, int n_in,
                              void* d_out, int out_size, void* d_ws, size_t ws_size,
                              hipStream_t stream) {
    const float* hidden = (const float*)d_in[0];
    const float* mask   = (const float*)d_in[1];
    const int*   arc    = (const int*)d_in[2];
    const float* Wq = (const float*)d_in[3];
    const float* bq = (const float*)d_in[4];
    const float* Wk = (const float*)d_in[5];
    const float* bk = (const float*)d_in[6];
    const float* Wv = (const float*)d_in[7];
    const float* bv = (const float*)d_in[8];
    const float* rel_k = (const float*)d_in[9];
    const float* rel_v = (const float*)d_in[10];
    const float* lng_k = (const float*)d_in[11];
    const float* lnb_k = (const float*)d_in[12];
    const float* lng_v = (const float*)d_in[13];
    const float* lnb_v = (const float*)d_in[14];
    float* out = (float*)d_out;

    char* p = (char*)d_ws;
    auto carve = [&](size_t bytes) { char* r = p; p += (bytes + 255) & ~(size_t)255; return r; };
    short* lnkb = (short*)carve((size_t)96 * DD * 2);
    short* lnvT = (short*)carve((size_t)DD * 96 * 2);
    short* hbf  = (short*)carve((size_t)BB * SS * HIDV * 2);
    short* WqT  = (short*)carve((size_t)HIDV * HIDV * 2);
    short* WkT  = (short*)carve((size_t)HIDV * HIDV * 2);
    short* WvT  = (short*)carve((size_t)HIDV * HIDV * 2);
    const size_t per = (size_t)BB * HH * SS * DD;
    short* qbuf = (short*)carve(per * 2);
    short* kbuf = (short*)carve(per * 2);
    short* vtb  = (short*)carve(per * 2);
    unsigned int* arcP = (unsigned int*)carve((size_t)BB * 128 * SS * 4);

    prep_ln_kernel<<<1, 256, 0, stream>>>(rel_k, rel_v, lng_k, lnb_k, lng_v, lnb_v, lnkb, lnvT);
    prep_fused_kernel<<<dim3(NCONV + NTRANS + NARC), 256, 0, stream>>>(
        hidden, hbf, Wq, Wk, Wv, WqT, WkT, WvT, arc, arcP);
    qkv_gemm_kernel<<<dim3(HIDV / 64, (BB * SS) / 64, 3), 256, 0, stream>>>(
        hbf, WqT, WkT, WvT, bq, bk, bv, qbuf, kbuf, vtb);
    attn_kernel<<<dim3(BB * HH * 8), 256, 0, stream>>>(
        qbuf, kbuf, vtb, arcP, mask, lnkb, lnvT, out);
}